// Round 5
// baseline (282.888 us; speedup 1.0000x reference)
//
#include <hip/hip_runtime.h>

#define NBINS 15
#define NCLS  100
#define NSEG  (NBINS * NCLS)   // 1500
#define NBLK  512              // 2 blocks/CU at BLK=1024 -> 32 waves/CU
#define BLK   1024
#define FBLK  256              // fused-reduce block size
#define SUMSCALE 2048.0f       // fixed-point scale for packed sum (20-bit field)
#define INV15 (1.0f / 15.0f)   // f32 edge arithmetic (round-2/5 proven vs np)

// native clang vector type — __builtin_nontemporal_load requires this
// (HIP_vector_type<float,4> is a class and is rejected).
typedef float nf4 __attribute__((ext_vector_type(4)));

// Per-float4 bin/accumulate. Exact searchsorted-right semantics:
// k = largest bin with edge <= p; strict > left edge and > THRESHOLD
// filters. One packed fire-and-forget LDS atomic per valid element:
// u32 = (1<<20) | round(p*2048). LDS atomics are block-local (32 banks,
// pipelined) — cheap. (Round-3 lesson: device-scope atomics to a tiny
// footprint serialize at the cross-XCD coherence point, +31 us. Never.)
__device__ __forceinline__ void proc_f4(nf4 v, int i,
                                        const int* __restrict__ labels,
                                        unsigned int* s_pk, unsigned int* s_ac)
{
    int row  = i / 25;              // compiler magic-div (i < 12.5M)
    int col0 = (i - row * 25) * 4;  // float4 never crosses a row (100%4==0)
    int lbl  = labels[row];
    float pv[4] = {v.x, v.y, v.z, v.w};
    #pragma unroll
    for (int j = 0; j < 4; ++j) {
        float p = pv[j];
        int c = col0 + j;
        // searchsorted(bins, p, 'right') - 1: largest k with bins[k] <= p
        int k = (int)(p * 15.0f);
        if (k < NBINS && (float)(k + 1) * INV15 <= p)      ++k;
        else if (k > 0 && (float)k * INV15 > p)            --k;
        float left = (float)k * INV15;
        if (p > 0.01f && k < NBINS && p > left) {
            int seg = c * NBINS + k;
            unsigned int pk = (1u << 20) | (unsigned int)(p * SUMSCALE + 0.5f);
            atomicAdd(&s_pk[seg], pk);
            if (lbl == c) atomicAdd(&s_ac[seg], 1u);
        }
    }
}

// Kernel 1: grid-stride stream, 2-way MLP (two independent float4 loads per
// iteration, split-half indexing), nontemporal (zero-reuse 200 MB stream,
// keep L2 for labels + partials). BLK=1024 x NBLK=512 keeps full occupancy
// (32 waves/CU) while aggregating 4x more elements per LDS flush:
// partU = 512 x 2*NSEG u32 = 6.1 MB.
__global__ __launch_bounds__(BLK) void calib_accum(
    const float* __restrict__ probas,
    const int*   __restrict__ labels,
    unsigned int* __restrict__ partU,   // [nblk][2*NSEG]
    int total4)
{
    __shared__ unsigned int s_pk[NSEG];   // packed: cnt<<20 | sum*2048
    __shared__ unsigned int s_ac[NSEG];   // label-match counts
    const int t = threadIdx.x;
    for (int i = t; i < NSEG; i += BLK) { s_pk[i] = 0u; s_ac[i] = 0u; }
    __syncthreads();

    const nf4* __restrict__ p4 = (const nf4*)probas;
    const int stride = gridDim.x * BLK;
    const int half4  = total4 >> 1;

    for (int i = blockIdx.x * BLK + t; i < half4; i += stride) {
        nf4 a = __builtin_nontemporal_load(&p4[i]);
        nf4 b = __builtin_nontemporal_load(&p4[i + half4]);
        proc_f4(a, i,         labels, s_pk, s_ac);
        proc_f4(b, i + half4, labels, s_pk, s_ac);
    }
    // odd total4 tail (not hit for N*C = 50M, kept for safety)
    if ((total4 & 1) && blockIdx.x == 0 && t == 0) {
        proc_f4(p4[total4 - 1], total4 - 1, labels, s_pk, s_ac);
    }
    __syncthreads();

    unsigned int* dst = partU + (size_t)blockIdx.x * (2 * NSEG);
    for (int s = t; s < NSEG; s += BLK) {
        dst[s]        = s_pk[s];
        dst[NSEG + s] = s_ac[s];
    }
}

// Kernel 2 (fused mid+fin): each block owns 32 segments; 8 threads per
// segment each reduce a contiguous chunk of partU blocks (coalesced:
// lanes ts=0..31 read 32 consecutive u32), then a 3-level LDS tree over
// the 8 chunk-partials, then divide + NaN + store. Integer-exact: any
// partial subset <= global total (cnt <= 500K, sumq <= 500K*2048 =
// 1.02e9 < 2^32, acc <= 500K).
__global__ __launch_bounds__(FBLK) void calib_fin2(
    const unsigned int* __restrict__ partU, int nblk,
    float*              __restrict__ out)   // [confs(1500), accs(1500), n(1500)]
{
    __shared__ unsigned int s_cnt[FBLK], s_sum[FBLK], s_acc[FBLK];
    const int t   = threadIdx.x;
    const int ts  = t & 31;          // segment lane within block
    const int tb  = t >> 5;          // chunk index 0..7
    const int seg = blockIdx.x * 32 + ts;
    const int chunk = (nblk + 7) >> 3;
    int b0 = tb * chunk;
    int b1 = b0 + chunk; if (b1 > nblk) b1 = nblk;

    unsigned int cnt = 0u, sumq = 0u, acc = 0u;
    if (seg < NSEG) {
        for (int b = b0; b < b1; ++b) {
            const unsigned int* src = partU + (size_t)b * (2 * NSEG);
            unsigned int pk = src[seg];
            cnt  += pk >> 20;
            sumq += pk & 0xFFFFFu;
            acc  += src[NSEG + seg];
        }
    }
    s_cnt[t] = cnt; s_sum[t] = sumq; s_acc[t] = acc;
    __syncthreads();
    #pragma unroll
    for (int off = 4; off >= 1; off >>= 1) {
        if (tb < off) {
            s_cnt[t] += s_cnt[t + off * 32];
            s_sum[t] += s_sum[t + off * 32];
            s_acc[t] += s_acc[t + off * 32];
        }
        __syncthreads();
    }
    if (tb == 0 && seg < NSEG) {
        unsigned int c = s_cnt[t], sq = s_sum[t], a = s_acc[t];
        float conf, accv;
        if (c > 0u) {
            float inv = 1.0f / (float)c;
            conf = (float)sq * (1.0f / SUMSCALE) * inv;
            accv = (float)a * inv;
        } else {
            conf = __int_as_float(0x7fc00000);
            accv = conf;
        }
        out[seg]            = conf;
        out[NSEG + seg]     = accv;
        out[2 * NSEG + seg] = (float)c;
    }
}

extern "C" void kernel_launch(void* const* d_in, const int* in_sizes, int n_in,
                              void* d_out, int out_size, void* d_ws, size_t ws_size,
                              hipStream_t stream) {
    const float* probas = (const float*)d_in[0];
    const int*   labels = (const int*)d_in[1];
    float* out = (float*)d_out;
    unsigned int* ws = (unsigned int*)d_ws;

    int total  = in_sizes[0];      // N*C = 50,000,000 (divisible by 4; C=100)
    int total4 = total / 4;

    // workspace: partU [nblk][2*NSEG] u32
    size_t ws_u32 = ws_size / sizeof(unsigned int);
    int nblk = (int)(ws_u32 / (2 * NSEG));
    if (nblk > NBLK) nblk = NBLK;
    if (nblk < 1) nblk = 1;

    unsigned int* partU = ws;

    calib_accum<<<nblk, BLK, 0, stream>>>(probas, labels, partU, total4);
    calib_fin2<<<(NSEG + 31) / 32, FBLK, 0, stream>>>(partU, nblk, out);
}